// Round 5
// baseline (2524.370 us; speedup 1.0000x reference)
//
#include <hip/hip_runtime.h>
#include <hip/hip_cooperative_groups.h>
namespace cg = cooperative_groups;

#define N 4096
#define D 10000
#define D4 2500          // D/4
#define C 10
#define NB 16            // number of 256-step blocks
#define B 256            // steps per block

// ---- workspace layout (float offsets) ----
#define AM_OFF    0                          // [C*D] = 100000
#define GLOC_OFF  100096                     // [16][256][256] = 1048576
#define S_OFF     (GLOC_OFF + NB*B*B)        // [N*C] scores vs current am
#define HV2_OFF   (S_OFF + N*C)              // [N] ||hv||^2
#define AN_OFF    (HV2_OFF + N)              // [16] running ||am_c||^2
#define ANF_OFF   (AN_OFF + 16)              // [16] final  ||am_c||^2
#define WLIST_OFF (ANF_OFF + 16)             // [N] packed j|pred<<8|lab<<12 (per-block at k*B)
#define NWRONG_OFF (WLIST_OFF + N)           // [NB]
#define MIST_OFF  (NWRONG_OFF + NB)          // [1]

// ---------------- build_am: segment-sum, float4, register accumulate + atomics ------------
__global__ __launch_bounds__(256) void build_am_kernel(float* __restrict__ am,
        const float* __restrict__ X, const int* __restrict__ labels){
    int d4 = blockIdx.x*256 + threadIdx.x;
    if (d4 >= D4) return;
    int i0 = blockIdx.y * (N/16);
    const float4* X4 = (const float4*)X;
    float4 acc[C];
    #pragma unroll
    for (int c=0;c<C;c++) acc[c] = make_float4(0.f,0.f,0.f,0.f);
    for (int i=i0; i<i0+(N/16); ++i){
        int lab = labels[i];
        float4 x = X4[(size_t)i*D4 + d4];
        #pragma unroll
        for (int c=0;c<C;c++){
            float m = (lab==c) ? 1.f : 0.f;
            acc[c].x += m*x.x; acc[c].y += m*x.y; acc[c].z += m*x.z; acc[c].w += m*x.w;
        }
    }
    #pragma unroll
    for (int c=0;c<C;c++){
        float* p = &am[(size_t)c*D + d4*4];
        atomicAdd(p+0, acc[c].x); atomicAdd(p+1, acc[c].y);
        atomicAdd(p+2, acc[c].z); atomicAdd(p+3, acc[c].w);
    }
}

// ---------------- row sum-of-squares of am -> out[c] ----------------
__global__ __launch_bounds__(256) void rownorm2_kernel(const float* __restrict__ am,
        float* __restrict__ out){
    int c = blockIdx.x, t = threadIdx.x;
    const float4* a4 = (const float4*)(am + (size_t)c*D);
    float p = 0.f;
    for (int d=t; d<D4; d+=256){ float4 v = a4[d]; p += v.x*v.x+v.y*v.y+v.z*v.z+v.w*v.w; }
    #pragma unroll
    for (int off=32; off>=1; off>>=1) p += __shfl_down(p, off);
    __shared__ float wsum[4];
    int wid = t>>6, lane = t&63;
    if (lane==0) wsum[wid]=p;
    __syncthreads();
    if (t==0) out[c] = wsum[0]+wsum[1]+wsum[2]+wsum[3];
}

// ---------------- block-diagonal Gram tiles (fp32, LDS XOR-swizzled, K-split) --------------
__global__ __launch_bounds__(256) void gram_kernel(const float* __restrict__ X,
        float* __restrict__ Gloc){
    __shared__ float Asm[32][68];   // transposed: [dd][row], swizzled
    __shared__ float Bsm[32][68];
    int bx = blockIdx.x;
    int k  = blockIdx.y;
    int p  = bx % 10;               // upper-triangle 64x64 tile pair
    int z  = bx / 10;               // K-split 0..7
    int ti = (p<4)?0:(p<7)?1:(p<9)?2:3;
    int st = (ti==0)?0:(ti==1)?4:(ti==2)?7:9;
    int tj = ti + (p - st);
    int rowA = k*B + ti*64;
    int rowB = k*B + tj*64;
    int t = threadIdx.x;
    int tx = t & 15, ty = t >> 4;
    float acc[4][4];
    #pragma unroll
    for (int i=0;i<4;i++)
        #pragma unroll
        for (int j=0;j<4;j++) acc[i][j]=0.f;

    for (int ch = z; ch*32 < D; ch += 8){
        int dbase = ch*32;
        int valid = D - dbase; if (valid > 32) valid = 32;
        #pragma unroll
        for (int f0 = 0; f0 < 512; f0 += 256){
            int f = f0 + t;
            int row = f >> 3, q = f & 7;
            float4 a = make_float4(0,0,0,0), b = make_float4(0,0,0,0);
            if (q*4 < valid){
                a = *(const float4*)&X[(size_t)(rowA + row)*D + dbase + q*4];
                b = *(const float4*)&X[(size_t)(rowB + row)*D + dbase + q*4];
            }
            int pr = row ^ (q<<3);
            Asm[q*4+0][pr]=a.x; Asm[q*4+1][pr]=a.y; Asm[q*4+2][pr]=a.z; Asm[q*4+3][pr]=a.w;
            Bsm[q*4+0][pr]=b.x; Bsm[q*4+1][pr]=b.y; Bsm[q*4+2][pr]=b.z; Bsm[q*4+3][pr]=b.w;
        }
        __syncthreads();
        #pragma unroll 4
        for (int dd=0; dd<32; ++dd){
            int sw = ((dd>>2)&7)<<3;
            const float4 av = *(const float4*)&Asm[dd][(ty*4) ^ sw];
            const float4 bv = *(const float4*)&Bsm[dd][(tx*4) ^ sw];
            float a4[4] = {av.x, av.y, av.z, av.w};
            float b4[4] = {bv.x, bv.y, bv.z, bv.w};
            #pragma unroll
            for (int i=0;i<4;i++)
                #pragma unroll
                for (int j=0;j<4;j++) acc[i][j] += a4[i]*b4[j];
        }
        __syncthreads();
    }
    float* G = Gloc + (size_t)k*B*B;
    int abase = ti*64 + ty*4;
    int bbase = tj*64 + tx*4;
    #pragma unroll
    for (int i=0;i<4;i++)
        #pragma unroll
        for (int j=0;j<4;j++)
            atomicAdd(&G[(abase+i)*B + (bbase+j)], acc[i][j]);
}

// ================= cooperative retrain: S-phase / seq-phase / apply-phase ==================
__global__ __launch_bounds__(256) void retrain_kernel(
        float* am, const float* __restrict__ X, const int* __restrict__ labels,
        const float* __restrict__ Gloc, float* S, float* hv2g, float* amnorm2,
        int* wrongList, int* nwrong, int* mistakes){
    cg::grid_group grid = cg::this_grid();
    const int bx = blockIdx.x, t = threadIdx.x;
    const float4* X4 = (const float4*)X;
    __shared__ float red[(C+1)*4];

    for (int k=0;k<NB;k++){
        const int base = k*B;

        // ---------- S phase: WG bx computes S[base+bx][*] and hv2 from CURRENT am ----------
        {
            int gj = base + bx;
            const float4* xr = X4 + (size_t)gj*D4;
            const float4* a4 = (const float4*)am;
            float p[C+1];
            #pragma unroll
            for (int v=0;v<C+1;v++) p[v]=0.f;
            for (int d=t; d<D4; d+=256){
                float4 x = xr[d];
                p[C] += x.x*x.x + x.y*x.y + x.z*x.z + x.w*x.w;
                #pragma unroll
                for (int c=0;c<C;c++){
                    float4 a = a4[(size_t)c*D4 + d];
                    p[c] += x.x*a.x + x.y*a.y + x.z*a.z + x.w*a.w;
                }
            }
            int wid=t>>6, lane=t&63;
            #pragma unroll
            for (int v=0; v<C+1; ++v){
                float x = p[v];
                #pragma unroll
                for (int off=32; off>=1; off>>=1) x += __shfl_down(x, off);
                if (lane==0) red[v*4+wid] = x;
            }
            __syncthreads();
            if (t < C+1){
                float r = red[t*4+0]+red[t*4+1]+red[t*4+2]+red[t*4+3];
                if (t < C) S[(size_t)gj*C + t] = r;
                else hv2g[gj] = r;
            }
            __syncthreads();
        }
        grid.sync();

        // ---------- seq phase: WG0, wave 0 only (proven round-4 body) ----------
        if (bx==0 && t<64){
            const int lane = t;
            const float* G = Gloc + (size_t)k*B*B;
            float s[4][C];
            float h2o[4]; int labo[4];
            #pragma unroll
            for (int q=0;q<4;q++){
                int j = q*64 + lane;
                #pragma unroll
                for (int c=0;c<C;c++) s[q][c] = S[(size_t)(base+j)*C + c];
                h2o[q] = hv2g[base + j];
                labo[q] = labels[base + j];
            }
            float an[C], rstd[C];
            #pragma unroll
            for (int c=0;c<C;c++){ an[c] = amnorm2[c]; rstd[c] = rsqrtf(an[c]); }

            int myPred[4], myWrong[4];
            #pragma unroll
            for (int q=0;q<4;q++){ myPred[q]=0; myWrong[q]=0; }

            float g[8][4];
            #pragma unroll
            for (int r=0;r<8;r++)
                #pragma unroll
                for (int sl=0;sl<4;sl++) g[r][sl] = G[(size_t)r*B + sl*64 + lane];

            #pragma unroll
            for (int q=0;q<4;q++){
                for (int jj8=0; jj8<8; ++jj8){
                    #pragma unroll
                    for (int u=0; u<8; ++u){
                        int jj = jj8*8 + u;
                        int j  = q*64 + jj;
                        float gcur[4];
                        #pragma unroll
                        for (int sl=0;sl<4;sl++) gcur[sl] = g[u][sl];
                        if (j+8 < B){
                            #pragma unroll
                            for (int sl=0;sl<4;sl++) g[u][sl] = G[(size_t)(j+8)*B + sl*64 + lane];
                        }
                        float best = s[q][0]*rstd[0]; int bi=0; float braw = s[q][0];
                        #pragma unroll
                        for (int c=1;c<C;c++){
                            float v = s[q][c]*rstd[c];
                            if (v>best){best=v;bi=c;braw=s[q][c];}
                        }
                        int labme = labo[q];
                        float slv = s[q][0];
                        #pragma unroll
                        for (int c=1;c<C;c++) slv = (c==labme)? s[q][c] : slv;
                        int wrongme = (bi != labme) ? 1 : 0;
                        if (lane == jj){ myPred[q]=bi; myWrong[q]=wrongme; }
                        int   pk    = __shfl(bi | (labme<<8) | (wrongme<<16), jj);
                        float brawB = __shfl(braw, jj);
                        float slvB  = __shfl(slv,  jj);
                        float h2b   = __shfl(h2o[q], jj);
                        int biB = pk & 255, labB = (pk>>8) & 255, wrongB = (pk>>16) & 1;
                        if (wrongB){
                            float anp = an[0], anl = an[0];
                            #pragma unroll
                            for (int c=1;c<C;c++){ anp=(c==biB)?an[c]:anp; anl=(c==labB)?an[c]:anl; }
                            float anp_new = anp - 2.f*brawB + h2b;
                            float anl_new = anl + 2.f*slvB  + h2b;
                            float rp = rsqrtf(anp_new), rl = rsqrtf(anl_new);
                            #pragma unroll
                            for (int c=0;c<C;c++){
                                an[c]   = (c==biB)? anp_new : (c==labB)? anl_new : an[c];
                                rstd[c] = (c==biB)? rp      : (c==labB)? rl      : rstd[c];
                            }
                            #pragma unroll
                            for (int c=0;c<C;c++){
                                float sg = (c==biB)? -1.f : (c==labB)? 1.f : 0.f;
                                #pragma unroll
                                for (int sl=0;sl<4;sl++) s[sl][c] += sg * gcur[sl];
                            }
                        }
                    }
                }
            }
            // compact wrong list for this block
            int ofs = 0;
            #pragma unroll
            for (int q=0;q<4;q++){
                unsigned long long m = __ballot(myWrong[q] != 0);
                if (myWrong[q]){
                    int pos = ofs + __popcll(m & ((1ull<<lane)-1ull));
                    wrongList[base + pos] = (q*64+lane) | (myPred[q]<<8) | (labo[q]<<12);
                }
                ofs += __popcll(m);
            }
            if (lane==0){
                nwrong[k] = ofs;
                atomicAdd(mistakes, ofs);
                #pragma unroll
                for (int c=0;c<C;c++) amnorm2[c] = an[c];
            }
        }
        grid.sync();

        // ---------- apply phase: WGs 0..9, exclusive float4-column ownership ----------
        if (bx < 10){
            int d4i = bx*256 + t;
            if (d4i < D4){
                int cnt = nwrong[k];
                if (cnt > 0){
                    float4 delta[C];
                    #pragma unroll
                    for (int c=0;c<C;c++) delta[c] = make_float4(0.f,0.f,0.f,0.f);
                    int touched = 0;
                    for (int w=0; w<cnt; ++w){
                        int pk = wrongList[base + w];
                        int j = pk & 255, pcl = (pk>>8)&15, lcl = (pk>>12)&15;
                        touched |= (1<<pcl) | (1<<lcl);
                        float4 x = X4[(size_t)(base+j)*D4 + d4i];
                        #pragma unroll
                        for (int c=0;c<C;c++){
                            float coef = ((c==pcl)? -1.f : 0.f) + ((c==lcl)? 1.f : 0.f);
                            delta[c].x += coef*x.x; delta[c].y += coef*x.y;
                            delta[c].z += coef*x.z; delta[c].w += coef*x.w;
                        }
                    }
                    float4* am4 = (float4*)am;
                    #pragma unroll
                    for (int c=0;c<C;c++){
                        if (touched & (1<<c)){
                            float4 v = am4[(size_t)c*D4 + d4i];
                            v.x += delta[c].x; v.y += delta[c].y;
                            v.z += delta[c].z; v.w += delta[c].w;
                            am4[(size_t)c*D4 + d4i] = v;
                        }
                    }
                }
            }
        }
        grid.sync();
    }
}

// ---------------- final predict: 4 rows/WG, float4, am reuse in registers ----------------
__global__ __launch_bounds__(256) void predict_kernel(const float* __restrict__ am,
        const float* __restrict__ X, const float* __restrict__ anf, float* __restrict__ outPred){
    int i0 = blockIdx.x*4, t = threadIdx.x;
    const float4* a4 = (const float4*)am;
    const float4* X4 = (const float4*)X;
    float p[4][C];
    #pragma unroll
    for (int r=0;r<4;r++)
        #pragma unroll
        for (int c=0;c<C;c++) p[r][c]=0.f;
    for (int d=t; d<D4; d+=256){
        float4 x0 = X4[(size_t)(i0+0)*D4 + d];
        float4 x1 = X4[(size_t)(i0+1)*D4 + d];
        float4 x2 = X4[(size_t)(i0+2)*D4 + d];
        float4 x3 = X4[(size_t)(i0+3)*D4 + d];
        #pragma unroll
        for (int c=0;c<C;c++){
            float4 a = a4[(size_t)c*D4 + d];
            p[0][c] += x0.x*a.x + x0.y*a.y + x0.z*a.z + x0.w*a.w;
            p[1][c] += x1.x*a.x + x1.y*a.y + x1.z*a.z + x1.w*a.w;
            p[2][c] += x2.x*a.x + x2.y*a.y + x2.z*a.z + x2.w*a.w;
            p[3][c] += x3.x*a.x + x3.y*a.y + x3.z*a.z + x3.w*a.w;
        }
    }
    __shared__ float red[4][C][4];
    int wid=t>>6, lane=t&63;
    #pragma unroll
    for (int r=0;r<4;r++)
        #pragma unroll
        for (int c=0;c<C;c++){
            float x = p[r][c];
            #pragma unroll
            for (int off=32; off>=1; off>>=1) x += __shfl_down(x, off);
            if (lane==0) red[r][c][wid] = x;
        }
    __syncthreads();
    if (t < 4){
        float best = -3.4e38f; int bi = 0;
        #pragma unroll
        for (int c=0;c<C;c++){
            float dot = red[t][c][0]+red[t][c][1]+red[t][c][2]+red[t][c][3];
            float v = dot * rsqrtf(anf[c]);
            if (v > best){ best = v; bi = c; }
        }
        outPred[i0 + t] = (float)bi;
    }
}

// ---------------- am copy + mistakes scalar ----------------
__global__ __launch_bounds__(256) void finalize_kernel(const float* __restrict__ am,
        const int* __restrict__ mistakes, float* __restrict__ out){
    int i = blockIdx.x*256 + threadIdx.x;
    if (i < C*D) out[i] = am[i];
    if (i == 0) out[C*D + N] = (float)(*mistakes);
}

extern "C" void kernel_launch(void* const* d_in, const int* in_sizes, int n_in,
                              void* d_out, int out_size, void* d_ws, size_t ws_size,
                              hipStream_t stream){
    const float* X      = (const float*)d_in[0];
    const int*   labels = (const int*)d_in[1];
    float* ws   = (float*)d_ws;
    float* am   = ws + AM_OFF;
    float* Gloc = ws + GLOC_OFF;
    float* S    = ws + S_OFF;
    float* hv2  = ws + HV2_OFF;
    float* an   = ws + AN_OFF;
    float* anf  = ws + ANF_OFF;
    int*   wlist  = (int*)(ws + WLIST_OFF);
    int*   nwrong = (int*)(ws + NWRONG_OFF);
    int*   mist   = (int*)(ws + MIST_OFF);
    float* out = (float*)d_out;

    hipMemsetAsync(am,   0, (size_t)C*D*sizeof(float), stream);
    hipMemsetAsync(Gloc, 0, (size_t)NB*B*B*sizeof(float), stream);
    hipMemsetAsync(mist, 0, sizeof(int), stream);

    build_am_kernel<<<dim3(10,16), 256, 0, stream>>>(am, X, labels);
    rownorm2_kernel<<<C, 256, 0, stream>>>(am, an);
    gram_kernel<<<dim3(80,NB), 256, 0, stream>>>(X, Gloc);

    {
        void* args[] = { (void*)&am, (void*)&X, (void*)&labels, (void*)&Gloc,
                         (void*)&S, (void*)&hv2, (void*)&an,
                         (void*)&wlist, (void*)&nwrong, (void*)&mist };
        hipLaunchCooperativeKernel((void*)retrain_kernel, dim3(256), dim3(256),
                                   args, 0, stream);
    }

    rownorm2_kernel<<<C, 256, 0, stream>>>(am, anf);
    predict_kernel<<<N/4, 256, 0, stream>>>(am, X, anf, out + (size_t)C*D);
    finalize_kernel<<<(C*D + 255)/256 + 1, 256, 0, stream>>>(am, mist, out);
}

// Round 6
// 1550.601 us; speedup vs baseline: 1.6280x; 1.6280x over previous
//
#include <hip/hip_runtime.h>

#define N 4096
#define D 10000
#define D4 2500          // D/4
#define C 10
#define NB 16            // number of 256-step blocks
#define B 256            // steps per block

#define SWG 64           // S-phase workgroups (4 rows each)
#define AWG 10           // apply-phase workgroups
#define NWG (SWG + AWG)  // retrain grid

// ---- workspace layout (float offsets) ----
#define AM_OFF    0                           // buf0 [100096]
#define AM2_OFF   100096                      // buf1 [100096]
#define GLOC_OFF  200192                      // [16][256][256]
#define S_OFF     (GLOC_OFF + NB*B*B)         // [N*C]
#define HV2_OFF   (S_OFF + N*C)               // [N]
#define AN_OFF    (HV2_OFF + N)               // [16] initial ||am_c||^2
#define ANF_OFF   (AN_OFF + 16)               // [16] final   ||am_c||^2
#define WLIST_OFF (ANF_OFF + 16)              // [N] packed j|pred<<8|lab<<12 per block
#define NWRONG_OFF (WLIST_OFF + N)            // [NB]
#define MIST_OFF  (NWRONG_OFF + NB)           // [1]
#define CTR_OFF   (MIST_OFF + 4)              // [2] ints: barrier ctr, seq flag

// ---------------- build_am: segment-sum, float4, register accumulate + atomics ------------
__global__ __launch_bounds__(256) void build_am_kernel(float* __restrict__ am,
        const float* __restrict__ X, const int* __restrict__ labels){
    int d4 = blockIdx.x*256 + threadIdx.x;
    if (d4 >= D4) return;
    int i0 = blockIdx.y * (N/16);
    const float4* X4 = (const float4*)X;
    float4 acc[C];
    #pragma unroll
    for (int c=0;c<C;c++) acc[c] = make_float4(0.f,0.f,0.f,0.f);
    for (int i=i0; i<i0+(N/16); ++i){
        int lab = labels[i];
        float4 x = X4[(size_t)i*D4 + d4];
        #pragma unroll
        for (int c=0;c<C;c++){
            float m = (lab==c) ? 1.f : 0.f;
            acc[c].x += m*x.x; acc[c].y += m*x.y; acc[c].z += m*x.z; acc[c].w += m*x.w;
        }
    }
    #pragma unroll
    for (int c=0;c<C;c++){
        float* p = &am[(size_t)c*D + d4*4];
        atomicAdd(p+0, acc[c].x); atomicAdd(p+1, acc[c].y);
        atomicAdd(p+2, acc[c].z); atomicAdd(p+3, acc[c].w);
    }
}

// ---------------- row sum-of-squares of am -> out[c] (initial only) ----------------
__global__ __launch_bounds__(256) void rownorm2_kernel(const float* __restrict__ am,
        float* __restrict__ out){
    int c = blockIdx.x, t = threadIdx.x;
    const float4* a4 = (const float4*)(am + (size_t)c*D);
    float p = 0.f;
    for (int d=t; d<D4; d+=256){ float4 v = a4[d]; p += v.x*v.x+v.y*v.y+v.z*v.z+v.w*v.w; }
    #pragma unroll
    for (int off=32; off>=1; off>>=1) p += __shfl_down(p, off);
    __shared__ float wsum[4];
    int wid = t>>6, lane = t&63;
    if (lane==0) wsum[wid]=p;
    __syncthreads();
    if (t==0) out[c] = wsum[0]+wsum[1]+wsum[2]+wsum[3];
}

// ---------------- block-diagonal Gram tiles (fp32, LDS XOR-swizzled, K-split) --------------
__global__ __launch_bounds__(256) void gram_kernel(const float* __restrict__ X,
        float* __restrict__ Gloc){
    __shared__ float Asm[32][68];
    __shared__ float Bsm[32][68];
    int bx = blockIdx.x;
    int k  = blockIdx.y;
    int p  = bx % 10;
    int z  = bx / 10;
    int ti = (p<4)?0:(p<7)?1:(p<9)?2:3;
    int st = (ti==0)?0:(ti==1)?4:(ti==2)?7:9;
    int tj = ti + (p - st);
    int rowA = k*B + ti*64;
    int rowB = k*B + tj*64;
    int t = threadIdx.x;
    int tx = t & 15, ty = t >> 4;
    float acc[4][4];
    #pragma unroll
    for (int i=0;i<4;i++)
        #pragma unroll
        for (int j=0;j<4;j++) acc[i][j]=0.f;

    for (int ch = z; ch*32 < D; ch += 8){
        int dbase = ch*32;
        int valid = D - dbase; if (valid > 32) valid = 32;
        #pragma unroll
        for (int f0 = 0; f0 < 512; f0 += 256){
            int f = f0 + t;
            int row = f >> 3, q = f & 7;
            float4 a = make_float4(0,0,0,0), b = make_float4(0,0,0,0);
            if (q*4 < valid){
                a = *(const float4*)&X[(size_t)(rowA + row)*D + dbase + q*4];
                b = *(const float4*)&X[(size_t)(rowB + row)*D + dbase + q*4];
            }
            int pr = row ^ (q<<3);
            Asm[q*4+0][pr]=a.x; Asm[q*4+1][pr]=a.y; Asm[q*4+2][pr]=a.z; Asm[q*4+3][pr]=a.w;
            Bsm[q*4+0][pr]=b.x; Bsm[q*4+1][pr]=b.y; Bsm[q*4+2][pr]=b.z; Bsm[q*4+3][pr]=b.w;
        }
        __syncthreads();
        #pragma unroll 4
        for (int dd=0; dd<32; ++dd){
            int sw = ((dd>>2)&7)<<3;
            const float4 av = *(const float4*)&Asm[dd][(ty*4) ^ sw];
            const float4 bv = *(const float4*)&Bsm[dd][(tx*4) ^ sw];
            float a4[4] = {av.x, av.y, av.z, av.w};
            float b4[4] = {bv.x, bv.y, bv.z, bv.w};
            #pragma unroll
            for (int i=0;i<4;i++)
                #pragma unroll
                for (int j=0;j<4;j++) acc[i][j] += a4[i]*b4[j];
        }
        __syncthreads();
    }
    float* G = Gloc + (size_t)k*B*B;
    int abase = ti*64 + ty*4;
    int bbase = tj*64 + tx*4;
    #pragma unroll
    for (int i=0;i<4;i++)
        #pragma unroll
        for (int j=0;j<4;j++)
            atomicAdd(&G[(abase+i)*B + (bbase+j)], acc[i][j]);
}

// ---------------- light barriers: relaxed-poll spin, acquire once on exit ----------------
__device__ inline void gbar(int* ctr, int target){
    __syncthreads();
    if (threadIdx.x == 0){
        __hip_atomic_fetch_add(ctr, 1, __ATOMIC_RELEASE, __HIP_MEMORY_SCOPE_AGENT);
        while (__hip_atomic_load(ctr, __ATOMIC_RELAXED, __HIP_MEMORY_SCOPE_AGENT) < target){}
        (void)__hip_atomic_load(ctr, __ATOMIC_ACQUIRE, __HIP_MEMORY_SCOPE_AGENT);
    }
    __syncthreads();
}
__device__ inline void flagwait(int* flag, int target){
    __syncthreads();
    if (threadIdx.x == 0){
        while (__hip_atomic_load(flag, __ATOMIC_RELAXED, __HIP_MEMORY_SCOPE_AGENT) < target){}
        (void)__hip_atomic_load(flag, __ATOMIC_ACQUIRE, __HIP_MEMORY_SCOPE_AGENT);
    }
    __syncthreads();
}

// ================= retrain: single dispatch, 74 WGs, 2 light syncs per block ==============
// iter k: [apply(k-1): stale->dst || S(k): stale + Gram-corrections(k-1)] ; bar ;
//         [WG0: seq(k)] ; flag(k+1) ; next
__global__ __launch_bounds__(256) void retrain_kernel(
        float* amA, float* amB, const float* __restrict__ X, const int* __restrict__ labels,
        const float* __restrict__ Gloc, float* __restrict__ S, float* __restrict__ hv2g,
        const float* __restrict__ an0, float* __restrict__ anf,
        int* __restrict__ wrongList, int* __restrict__ nwrong,
        int* __restrict__ mist, int* ctr, int* flag){
    const int bx = blockIdx.x, t = threadIdx.x;
    const float4* X4 = (const float4*)X;
    __shared__ float red[4][C+1][4];

    float an[C], rstd[C];
    int mistakes_total = 0;
    #pragma unroll
    for (int c=0;c<C;c++){ an[c]=an0[c]; rstd[c]=rsqrtf(an[c]); }

    for (int k=0; k<=NB; ++k){
        const float4* stale4 = (const float4*)((k==0)? amA : ((k&1)? amA : amB));
        float4* dst4 = (float4*)((k&1)? amB : amA);
        const int prevCnt = (k>=1)? nwrong[k-1] : 0;
        const int pbase = (k-1)*B;

        if (bx < SWG){
            if (k < NB){
                // ---------- S(k): 4 rows per WG vs stale am ----------
                int gj0 = k*B + bx*4;
                float p[4][C]; float px[4];
                #pragma unroll
                for (int r=0;r<4;r++){ px[r]=0.f;
                    #pragma unroll
                    for (int c=0;c<C;c++) p[r][c]=0.f; }
                for (int d=t; d<D4; d+=256){
                    float4 x0 = X4[(size_t)(gj0+0)*D4 + d];
                    float4 x1 = X4[(size_t)(gj0+1)*D4 + d];
                    float4 x2 = X4[(size_t)(gj0+2)*D4 + d];
                    float4 x3 = X4[(size_t)(gj0+3)*D4 + d];
                    px[0] += x0.x*x0.x + x0.y*x0.y + x0.z*x0.z + x0.w*x0.w;
                    px[1] += x1.x*x1.x + x1.y*x1.y + x1.z*x1.z + x1.w*x1.w;
                    px[2] += x2.x*x2.x + x2.y*x2.y + x2.z*x2.z + x2.w*x2.w;
                    px[3] += x3.x*x3.x + x3.y*x3.y + x3.z*x3.z + x3.w*x3.w;
                    #pragma unroll
                    for (int c=0;c<C;c++){
                        float4 a = stale4[(size_t)c*D4 + d];
                        p[0][c] += x0.x*a.x + x0.y*a.y + x0.z*a.z + x0.w*a.w;
                        p[1][c] += x1.x*a.x + x1.y*a.y + x1.z*a.z + x1.w*a.w;
                        p[2][c] += x2.x*a.x + x2.y*a.y + x2.z*a.z + x2.w*a.w;
                        p[3][c] += x3.x*a.x + x3.y*a.y + x3.z*a.z + x3.w*a.w;
                    }
                }
                // corrections from block k-1's wrongs: S += sign * (hv_w . hv_j)
                for (int w=0; w<prevCnt; ++w){
                    int pk = wrongList[pbase + w];
                    int jw = pk & 255, pcl = (pk>>8)&15, lcl = (pk>>12)&15;
                    const float4* xw = X4 + (size_t)(pbase + jw)*D4;
                    float g0=0.f,g1=0.f,g2=0.f,g3=0.f;
                    for (int d=t; d<D4; d+=256){
                        float4 xv = xw[d];
                        float4 x0 = X4[(size_t)(gj0+0)*D4 + d];
                        float4 x1 = X4[(size_t)(gj0+1)*D4 + d];
                        float4 x2 = X4[(size_t)(gj0+2)*D4 + d];
                        float4 x3 = X4[(size_t)(gj0+3)*D4 + d];
                        g0 += x0.x*xv.x + x0.y*xv.y + x0.z*xv.z + x0.w*xv.w;
                        g1 += x1.x*xv.x + x1.y*xv.y + x1.z*xv.z + x1.w*xv.w;
                        g2 += x2.x*xv.x + x2.y*xv.y + x2.z*xv.z + x2.w*xv.w;
                        g3 += x3.x*xv.x + x3.y*xv.y + x3.z*xv.z + x3.w*xv.w;
                    }
                    #pragma unroll
                    for (int c=0;c<C;c++){
                        float sg = ((c==lcl)?1.f:0.f) - ((c==pcl)?1.f:0.f);
                        p[0][c] += sg*g0; p[1][c] += sg*g1; p[2][c] += sg*g2; p[3][c] += sg*g3;
                    }
                }
                int wid=t>>6, lane=t&63;
                #pragma unroll
                for (int r=0;r<4;r++){
                    #pragma unroll
                    for (int v=0; v<C+1; ++v){
                        float x = (v<C)? p[r][v] : px[r];
                        #pragma unroll
                        for (int off=32; off>=1; off>>=1) x += __shfl_down(x, off);
                        if (lane==0) red[r][v][wid] = x;
                    }
                }
                __syncthreads();
                if (t < 4*(C+1)){
                    int r = t/(C+1), v = t%(C+1);
                    float s = red[r][v][0]+red[r][v][1]+red[r][v][2]+red[r][v][3];
                    if (v < C) S[(size_t)(gj0+r)*C + v] = s;
                    else hv2g[gj0 + r] = s;
                }
            }
        } else {
            if (k >= 1){
                // ---------- apply(k-1): stale + corrections -> dst (exclusive columns) ----
                int d4i = (bx - SWG)*256 + t;
                if (d4i < D4){
                    float4 delta[C];
                    #pragma unroll
                    for (int c=0;c<C;c++) delta[c] = make_float4(0.f,0.f,0.f,0.f);
                    for (int w=0; w<prevCnt; ++w){
                        int pk = wrongList[pbase + w];
                        int j = pk & 255, pcl = (pk>>8)&15, lcl = (pk>>12)&15;
                        float4 x = X4[(size_t)(pbase+j)*D4 + d4i];
                        #pragma unroll
                        for (int c=0;c<C;c++){
                            float coef = ((c==pcl)? -1.f : 0.f) + ((c==lcl)? 1.f : 0.f);
                            delta[c].x += coef*x.x; delta[c].y += coef*x.y;
                            delta[c].z += coef*x.z; delta[c].w += coef*x.w;
                        }
                    }
                    #pragma unroll
                    for (int c=0;c<C;c++){
                        float4 v = stale4[(size_t)c*D4 + d4i];
                        v.x += delta[c].x; v.y += delta[c].y;
                        v.z += delta[c].z; v.w += delta[c].w;
                        dst4[(size_t)c*D4 + d4i] = v;
                    }
                }
            }
        }
        if (k == NB) break;

        gbar(ctr, NWG*(k+1));

        // ---------- seq(k): WG0 wave0 ----------
        if (bx==0 && t<64){
            const int lane = t;
            const int base = k*B;
            const float* G = Gloc + (size_t)k*B*B;
            float s[4][C];
            float h2o[4]; int labo[4];
            #pragma unroll
            for (int q=0;q<4;q++){
                int j = q*64 + lane;
                #pragma unroll
                for (int c=0;c<C;c++) s[q][c] = S[(size_t)(base+j)*C + c];
                h2o[q] = hv2g[base + j];
                labo[q] = labels[base + j];
            }
            int myPred[4], myWrong[4];
            #pragma unroll
            for (int q=0;q<4;q++){ myPred[q]=0; myWrong[q]=0; }

            float g[8][4];
            #pragma unroll
            for (int r=0;r<8;r++)
                #pragma unroll
                for (int sl=0;sl<4;sl++) g[r][sl] = G[(size_t)r*B + sl*64 + lane];

            #pragma unroll
            for (int q=0;q<4;q++){
                for (int jj8=0; jj8<8; ++jj8){
                    #pragma unroll
                    for (int u=0; u<8; ++u){
                        int jj = jj8*8 + u;
                        int j  = q*64 + jj;
                        float gcur[4];
                        #pragma unroll
                        for (int sl=0;sl<4;sl++) gcur[sl] = g[u][sl];
                        if (j+8 < B){
                            #pragma unroll
                            for (int sl=0;sl<4;sl++) g[u][sl] = G[(size_t)(j+8)*B + sl*64 + lane];
                        }
                        float best = s[q][0]*rstd[0]; int bi=0; float braw = s[q][0];
                        #pragma unroll
                        for (int c=1;c<C;c++){
                            float v = s[q][c]*rstd[c];
                            if (v>best){best=v;bi=c;braw=s[q][c];}
                        }
                        int labme = labo[q];
                        float slv = s[q][0];
                        #pragma unroll
                        for (int c=1;c<C;c++) slv = (c==labme)? s[q][c] : slv;
                        int wrongme = (bi != labme) ? 1 : 0;
                        if (lane == jj){ myPred[q]=bi; myWrong[q]=wrongme; }
                        int   pk    = __shfl(bi | (labme<<8) | (wrongme<<16), jj);
                        float brawB = __shfl(braw, jj);
                        float slvB  = __shfl(slv,  jj);
                        float h2b   = __shfl(h2o[q], jj);
                        int biB = pk & 255, labB = (pk>>8) & 255, wrongB = (pk>>16) & 1;
                        if (wrongB){
                            float anp = an[0], anl = an[0];
                            #pragma unroll
                            for (int c=1;c<C;c++){ anp=(c==biB)?an[c]:anp; anl=(c==labB)?an[c]:anl; }
                            float anp_new = anp - 2.f*brawB + h2b;
                            float anl_new = anl + 2.f*slvB  + h2b;
                            float rp = rsqrtf(anp_new), rl = rsqrtf(anl_new);
                            #pragma unroll
                            for (int c=0;c<C;c++){
                                an[c]   = (c==biB)? anp_new : (c==labB)? anl_new : an[c];
                                rstd[c] = (c==biB)? rp      : (c==labB)? rl      : rstd[c];
                            }
                            #pragma unroll
                            for (int c=0;c<C;c++){
                                float sg = (c==biB)? -1.f : (c==labB)? 1.f : 0.f;
                                #pragma unroll
                                for (int sl=0;sl<4;sl++) s[sl][c] += sg * gcur[sl];
                            }
                        }
                    }
                }
            }
            int ofs = 0;
            #pragma unroll
            for (int q=0;q<4;q++){
                unsigned long long m = __ballot(myWrong[q] != 0);
                if (myWrong[q]){
                    int pos = ofs + __popcll(m & ((1ull<<lane)-1ull));
                    wrongList[base + pos] = (q*64+lane) | (myPred[q]<<8) | (labo[q]<<12);
                }
                ofs += __popcll(m);
            }
            mistakes_total += ofs;
            if (lane==0){
                nwrong[k] = ofs;
                __hip_atomic_store(flag, k+1, __ATOMIC_RELEASE, __HIP_MEMORY_SCOPE_AGENT);
            }
        }
        flagwait(flag, k+1);
    }

    if (bx==0 && t==0){
        mist[0] = mistakes_total;
        #pragma unroll
        for (int c=0;c<C;c++) anf[c] = an[c];
    }
}

// ---------------- final predict: 4 rows/WG, float4, am reuse in registers ----------------
__global__ __launch_bounds__(256) void predict_kernel(const float* __restrict__ am,
        const float* __restrict__ X, const float* __restrict__ anf, float* __restrict__ outPred){
    int i0 = blockIdx.x*4, t = threadIdx.x;
    const float4* a4 = (const float4*)am;
    const float4* X4 = (const float4*)X;
    float p[4][C];
    #pragma unroll
    for (int r=0;r<4;r++)
        #pragma unroll
        for (int c=0;c<C;c++) p[r][c]=0.f;
    for (int d=t; d<D4; d+=256){
        float4 x0 = X4[(size_t)(i0+0)*D4 + d];
        float4 x1 = X4[(size_t)(i0+1)*D4 + d];
        float4 x2 = X4[(size_t)(i0+2)*D4 + d];
        float4 x3 = X4[(size_t)(i0+3)*D4 + d];
        #pragma unroll
        for (int c=0;c<C;c++){
            float4 a = a4[(size_t)c*D4 + d];
            p[0][c] += x0.x*a.x + x0.y*a.y + x0.z*a.z + x0.w*a.w;
            p[1][c] += x1.x*a.x + x1.y*a.y + x1.z*a.z + x1.w*a.w;
            p[2][c] += x2.x*a.x + x2.y*a.y + x2.z*a.z + x2.w*a.w;
            p[3][c] += x3.x*a.x + x3.y*a.y + x3.z*a.z + x3.w*a.w;
        }
    }
    __shared__ float red[4][C][4];
    int wid=t>>6, lane=t&63;
    #pragma unroll
    for (int r=0;r<4;r++)
        #pragma unroll
        for (int c=0;c<C;c++){
            float x = p[r][c];
            #pragma unroll
            for (int off=32; off>=1; off>>=1) x += __shfl_down(x, off);
            if (lane==0) red[r][c][wid] = x;
        }
    __syncthreads();
    if (t < 4){
        float best = -3.4e38f; int bi = 0;
        #pragma unroll
        for (int c=0;c<C;c++){
            float dot = red[t][c][0]+red[t][c][1]+red[t][c][2]+red[t][c][3];
            float v = dot * rsqrtf(anf[c]);
            if (v > best){ best = v; bi = c; }
        }
        outPred[i0 + t] = (float)bi;
    }
}

// ---------------- am copy + mistakes scalar ----------------
__global__ __launch_bounds__(256) void finalize_kernel(const float* __restrict__ am,
        const int* __restrict__ mistakes, float* __restrict__ out){
    int i = blockIdx.x*256 + threadIdx.x;
    if (i < C*D) out[i] = am[i];
    if (i == 0) out[C*D + N] = (float)(*mistakes);
}

extern "C" void kernel_launch(void* const* d_in, const int* in_sizes, int n_in,
                              void* d_out, int out_size, void* d_ws, size_t ws_size,
                              hipStream_t stream){
    const float* X      = (const float*)d_in[0];
    const int*   labels = (const int*)d_in[1];
    float* ws   = (float*)d_ws;
    float* amA  = ws + AM_OFF;
    float* amB  = ws + AM2_OFF;
    float* Gloc = ws + GLOC_OFF;
    float* S    = ws + S_OFF;
    float* hv2  = ws + HV2_OFF;
    float* an   = ws + AN_OFF;
    float* anf  = ws + ANF_OFF;
    int*   wlist  = (int*)(ws + WLIST_OFF);
    int*   nwrong = (int*)(ws + NWRONG_OFF);
    int*   mist   = (int*)(ws + MIST_OFF);
    int*   ctr    = (int*)(ws + CTR_OFF);
    int*   flag   = ctr + 1;
    float* out = (float*)d_out;

    hipMemsetAsync(amA,  0, (size_t)C*D*sizeof(float), stream);
    hipMemsetAsync(Gloc, 0, (size_t)NB*B*B*sizeof(float), stream);
    hipMemsetAsync(ctr,  0, 2*sizeof(int), stream);

    build_am_kernel<<<dim3(10,16), 256, 0, stream>>>(amA, X, labels);
    rownorm2_kernel<<<C, 256, 0, stream>>>(amA, an);
    gram_kernel<<<dim3(80,NB), 256, 0, stream>>>(X, Gloc);

    retrain_kernel<<<NWG, 256, 0, stream>>>(amA, amB, X, labels, Gloc, S, hv2,
                                            an, anf, wlist, nwrong, mist, ctr, flag);

    predict_kernel<<<N/4, 256, 0, stream>>>(amA, X, anf, out + (size_t)C*D);
    finalize_kernel<<<(C*D + 255)/256 + 1, 256, 0, stream>>>(amA, mist, out);
}

// Round 7
// 1493.074 us; speedup vs baseline: 1.6907x; 1.0385x over previous
//
#include <hip/hip_runtime.h>

#define N 4096
#define D 10000
#define D4 2500          // D/4
#define C 10
#define NB 16            // number of 256-step blocks
#define B 256            // steps per block
#define CWG 32           // corrector WGs
#define ROWS 8           // rows per corrector WG
#define RWG (CWG + 1)    // retrain grid size

// ---- workspace layout (float offsets) ----
#define AM_OFF    0                            // [C*D] = 100000 (pad 100096)
#define GLOC_OFF  100096                       // [16][256][256]
#define S0_OFF    (GLOC_OFF + NB*B*B)          // [N*C] initial scores
#define SFIN_OFF  (S0_OFF + N*C)               // [N*C] corrected scores
#define HV2_OFF   (SFIN_OFF + N*C)             // [N]
#define AN_OFF    (HV2_OFF + N)                // [16] initial ||am_c||^2
#define ANF_OFF   (AN_OFF + 16)                // [16] final   ||am_c||^2
#define WLIST_OFF (ANF_OFF + 16)               // [N] packed gidx|pred<<12|lab<<16
#define WCUM_OFF  (WLIST_OFF + N)              // [32] ints, Wcum[k]=wrongs before block k
#define SLOTS_OFF (WCUM_OFF + 32)              // [RWG*32] ints, stride-32 arrival slots
#define FLAG_OFF  (SLOTS_OFF + RWG*32)         // [1] int
#define MIST_OFF  (FLAG_OFF + 8)               // [1] int

// ---------------- build_am: segment-sum, float4, register accumulate + atomics ------------
__global__ __launch_bounds__(256) void build_am_kernel(float* __restrict__ am,
        const float* __restrict__ X, const int* __restrict__ labels){
    int d4 = blockIdx.x*256 + threadIdx.x;
    if (d4 >= D4) return;
    int i0 = blockIdx.y * (N/16);
    const float4* X4 = (const float4*)X;
    float4 acc[C];
    #pragma unroll
    for (int c=0;c<C;c++) acc[c] = make_float4(0.f,0.f,0.f,0.f);
    for (int i=i0; i<i0+(N/16); ++i){
        int lab = labels[i];
        float4 x = X4[(size_t)i*D4 + d4];
        #pragma unroll
        for (int c=0;c<C;c++){
            float m = (lab==c) ? 1.f : 0.f;
            acc[c].x += m*x.x; acc[c].y += m*x.y; acc[c].z += m*x.z; acc[c].w += m*x.w;
        }
    }
    #pragma unroll
    for (int c=0;c<C;c++){
        float* p = &am[(size_t)c*D + d4*4];
        atomicAdd(p+0, acc[c].x); atomicAdd(p+1, acc[c].y);
        atomicAdd(p+2, acc[c].z); atomicAdd(p+3, acc[c].w);
    }
}

// ---------------- row sum-of-squares of am -> out[c] ----------------
__global__ __launch_bounds__(256) void rownorm2_kernel(const float* __restrict__ am,
        float* __restrict__ out){
    int c = blockIdx.x, t = threadIdx.x;
    const float4* a4 = (const float4*)(am + (size_t)c*D);
    float p = 0.f;
    for (int d=t; d<D4; d+=256){ float4 v = a4[d]; p += v.x*v.x+v.y*v.y+v.z*v.z+v.w*v.w; }
    #pragma unroll
    for (int off=32; off>=1; off>>=1) p += __shfl_down(p, off);
    __shared__ float wsum[4];
    int wid = t>>6, lane = t&63;
    if (lane==0) wsum[wid]=p;
    __syncthreads();
    if (t==0) out[c] = wsum[0]+wsum[1]+wsum[2]+wsum[3];
}

// ---------------- block-diagonal Gram tiles (fp32, LDS XOR-swizzled, K-split) --------------
__global__ __launch_bounds__(256) void gram_kernel(const float* __restrict__ X,
        float* __restrict__ Gloc){
    __shared__ float Asm[32][68];
    __shared__ float Bsm[32][68];
    int bx = blockIdx.x;
    int k  = blockIdx.y;
    int p  = bx % 10;
    int z  = bx / 10;
    int ti = (p<4)?0:(p<7)?1:(p<9)?2:3;
    int st = (ti==0)?0:(ti==1)?4:(ti==2)?7:9;
    int tj = ti + (p - st);
    int rowA = k*B + ti*64;
    int rowB = k*B + tj*64;
    int t = threadIdx.x;
    int tx = t & 15, ty = t >> 4;
    float acc[4][4];
    #pragma unroll
    for (int i=0;i<4;i++)
        #pragma unroll
        for (int j=0;j<4;j++) acc[i][j]=0.f;

    for (int ch = z; ch*32 < D; ch += 8){
        int dbase = ch*32;
        int valid = D - dbase; if (valid > 32) valid = 32;
        #pragma unroll
        for (int f0 = 0; f0 < 512; f0 += 256){
            int f = f0 + t;
            int row = f >> 3, q = f & 7;
            float4 a = make_float4(0,0,0,0), b = make_float4(0,0,0,0);
            if (q*4 < valid){
                a = *(const float4*)&X[(size_t)(rowA + row)*D + dbase + q*4];
                b = *(const float4*)&X[(size_t)(rowB + row)*D + dbase + q*4];
            }
            int pr = row ^ (q<<3);
            Asm[q*4+0][pr]=a.x; Asm[q*4+1][pr]=a.y; Asm[q*4+2][pr]=a.z; Asm[q*4+3][pr]=a.w;
            Bsm[q*4+0][pr]=b.x; Bsm[q*4+1][pr]=b.y; Bsm[q*4+2][pr]=b.z; Bsm[q*4+3][pr]=b.w;
        }
        __syncthreads();
        #pragma unroll 4
        for (int dd=0; dd<32; ++dd){
            int sw = ((dd>>2)&7)<<3;
            const float4 av = *(const float4*)&Asm[dd][(ty*4) ^ sw];
            const float4 bv = *(const float4*)&Bsm[dd][(tx*4) ^ sw];
            float a4[4] = {av.x, av.y, av.z, av.w};
            float b4[4] = {bv.x, bv.y, bv.z, bv.w};
            #pragma unroll
            for (int i=0;i<4;i++)
                #pragma unroll
                for (int j=0;j<4;j++) acc[i][j] += a4[i]*b4[j];
        }
        __syncthreads();
    }
    float* G = Gloc + (size_t)k*B*B;
    int abase = ti*64 + ty*4;
    int bbase = tj*64 + tx*4;
    #pragma unroll
    for (int i=0;i<4;i++)
        #pragma unroll
        for (int j=0;j<4;j++)
            atomicAdd(&G[(abase+i)*B + (bbase+j)], acc[i][j]);
}

// ---------------- S0[j][c] = am0_c . hv_j for ALL samples (+ hv2), 4 rows/WG ----------------
__global__ __launch_bounds__(256) void s0_kernel(const float* __restrict__ am,
        const float* __restrict__ X, float* __restrict__ S0, float* __restrict__ hv2){
    int gj0 = blockIdx.x*4;
    int t = threadIdx.x;
    const float4* X4 = (const float4*)X;
    const float4* a4 = (const float4*)am;
    float p[4][C]; float px[4];
    #pragma unroll
    for (int r=0;r<4;r++){ px[r]=0.f;
        #pragma unroll
        for (int c=0;c<C;c++) p[r][c]=0.f; }
    for (int d=t; d<D4; d+=256){
        float4 x0 = X4[(size_t)(gj0+0)*D4 + d];
        float4 x1 = X4[(size_t)(gj0+1)*D4 + d];
        float4 x2 = X4[(size_t)(gj0+2)*D4 + d];
        float4 x3 = X4[(size_t)(gj0+3)*D4 + d];
        px[0] += x0.x*x0.x + x0.y*x0.y + x0.z*x0.z + x0.w*x0.w;
        px[1] += x1.x*x1.x + x1.y*x1.y + x1.z*x1.z + x1.w*x1.w;
        px[2] += x2.x*x2.x + x2.y*x2.y + x2.z*x2.z + x2.w*x2.w;
        px[3] += x3.x*x3.x + x3.y*x3.y + x3.z*x3.z + x3.w*x3.w;
        #pragma unroll
        for (int c=0;c<C;c++){
            float4 a = a4[(size_t)c*D4 + d];
            p[0][c] += x0.x*a.x + x0.y*a.y + x0.z*a.z + x0.w*a.w;
            p[1][c] += x1.x*a.x + x1.y*a.y + x1.z*a.z + x1.w*a.w;
            p[2][c] += x2.x*a.x + x2.y*a.y + x2.z*a.z + x2.w*a.w;
            p[3][c] += x3.x*a.x + x3.y*a.y + x3.z*a.z + x3.w*a.w;
        }
    }
    __shared__ float red[4][C+1][4];
    int wid=t>>6, lane=t&63;
    #pragma unroll
    for (int r=0;r<4;r++){
        #pragma unroll
        for (int v=0; v<C+1; ++v){
            float x = (v<C)? p[r][v] : px[r];
            #pragma unroll
            for (int off=32; off>=1; off>>=1) x += __shfl_down(x, off);
            if (lane==0) red[r][v][wid] = x;
        }
    }
    __syncthreads();
    if (t < 4*(C+1)){
        int r = t/(C+1), v = t%(C+1);
        float s = red[r][v][0]+red[r][v][1]+red[r][v][2]+red[r][v][3];
        if (v < C) S0[(size_t)(gj0+r)*C + v] = s;
        else hv2[gj0 + r] = s;
    }
}

// ================= retrain: 33 WGs; WG0 = sequencer, WGs 1..32 = correctors ================
// No am updates in the loop. S_final(k) = S0(k) + sum over cumulative wrongs of sg*(hv_w.hv_j).
// Sync: per-WG arrival slot STORES (no RMW) swept lane-parallel by WG0; one flag broadcast.
__global__ __launch_bounds__(256) void retrain_kernel(
        const float* __restrict__ X, const int* __restrict__ labels,
        const float* __restrict__ Gloc, const float* __restrict__ S0,
        float* __restrict__ Sfin, const float* __restrict__ hv2g,
        const float* __restrict__ an0, float* __restrict__ anf,
        int* __restrict__ wrongList, int* __restrict__ Wcum,
        int* slots, int* flag, int* __restrict__ mist){
    const int bx = blockIdx.x, t = threadIdx.x;
    const float4* X4 = (const float4*)X;

    if (bx == 0){
        // ---------------- sequencer ----------------
        float an[C], rstd[C];
        #pragma unroll
        for (int c=0;c<C;c++){ an[c]=an0[c]; rstd[c]=rsqrtf(an[c]); }
        int Wtot = 0;
        for (int k=0; k<NB; ++k){
            // wait: S_final(k) complete (correctors' slot >= k)
            if (t < CWG){
                while (__hip_atomic_load(&slots[(1+t)*32], __ATOMIC_RELAXED,
                                         __HIP_MEMORY_SCOPE_AGENT) < k)
                    __builtin_amdgcn_s_sleep(1);
            }
            __syncthreads();
            if (t==0) (void)__hip_atomic_load(&slots[32], __ATOMIC_ACQUIRE,
                                              __HIP_MEMORY_SCOPE_AGENT);
            __syncthreads();

            if (t < 64){
                const int lane = t;
                const int base = k*B;
                const float* G = Gloc + (size_t)k*B*B;
                float s[4][C];
                float h2o[4]; int labo[4];
                #pragma unroll
                for (int q=0;q<4;q++){
                    int j = q*64 + lane;
                    #pragma unroll
                    for (int c=0;c<C;c++) s[q][c] = Sfin[(size_t)(base+j)*C + c];
                    h2o[q] = hv2g[base + j];
                    labo[q] = labels[base + j];
                }
                int myPred[4], myWrong[4];
                #pragma unroll
                for (int q=0;q<4;q++){ myPred[q]=0; myWrong[q]=0; }

                float g[8][4];
                #pragma unroll
                for (int r=0;r<8;r++)
                    #pragma unroll
                    for (int sl=0;sl<4;sl++) g[r][sl] = G[(size_t)r*B + sl*64 + lane];

                #pragma unroll
                for (int q=0;q<4;q++){
                    for (int jj8=0; jj8<8; ++jj8){
                        #pragma unroll
                        for (int u=0; u<8; ++u){
                            int jj = jj8*8 + u;
                            int j  = q*64 + jj;
                            float gcur[4];
                            #pragma unroll
                            for (int sl=0;sl<4;sl++) gcur[sl] = g[u][sl];
                            if (j+8 < B){
                                #pragma unroll
                                for (int sl=0;sl<4;sl++)
                                    g[u][sl] = G[(size_t)(j+8)*B + sl*64 + lane];
                            }
                            float best = s[q][0]*rstd[0]; int bi=0; float braw = s[q][0];
                            #pragma unroll
                            for (int c=1;c<C;c++){
                                float v = s[q][c]*rstd[c];
                                if (v>best){best=v;bi=c;braw=s[q][c];}
                            }
                            int labme = labo[q];
                            float slv = s[q][0];
                            #pragma unroll
                            for (int c=1;c<C;c++) slv = (c==labme)? s[q][c] : slv;
                            int wrongme = (bi != labme) ? 1 : 0;
                            if (lane == jj){ myPred[q]=bi; myWrong[q]=wrongme; }
                            int   pk    = __shfl(bi | (labme<<8) | (wrongme<<16), jj);
                            float brawB = __shfl(braw, jj);
                            float slvB  = __shfl(slv,  jj);
                            float h2b   = __shfl(h2o[q], jj);
                            int biB = pk & 255, labB = (pk>>8) & 255, wrongB = (pk>>16) & 1;
                            if (wrongB){
                                float anp = an[0], anl = an[0];
                                #pragma unroll
                                for (int c=1;c<C;c++){ anp=(c==biB)?an[c]:anp;
                                                       anl=(c==labB)?an[c]:anl; }
                                float anp_new = anp - 2.f*brawB + h2b;
                                float anl_new = anl + 2.f*slvB  + h2b;
                                float rp = rsqrtf(anp_new), rl = rsqrtf(anl_new);
                                #pragma unroll
                                for (int c=0;c<C;c++){
                                    an[c]   = (c==biB)? anp_new : (c==labB)? anl_new : an[c];
                                    rstd[c] = (c==biB)? rp      : (c==labB)? rl      : rstd[c];
                                }
                                #pragma unroll
                                for (int c=0;c<C;c++){
                                    float sg = (c==biB)? -1.f : (c==labB)? 1.f : 0.f;
                                    #pragma unroll
                                    for (int sl=0;sl<4;sl++) s[sl][c] += sg * gcur[sl];
                                }
                            }
                        }
                    }
                }
                // append wrongs to the cumulative list (packed gidx|pred<<12|lab<<16)
                int ofs = 0;
                #pragma unroll
                for (int q=0;q<4;q++){
                    unsigned long long m = __ballot(myWrong[q] != 0);
                    if (myWrong[q]){
                        int pos = ofs + __popcll(m & ((1ull<<lane)-1ull));
                        wrongList[Wtot + pos] = (base + q*64 + lane)
                                              | (myPred[q]<<12) | (labo[q]<<16);
                    }
                    ofs += __popcll(m);
                }
                Wtot += ofs;
            }
            __syncthreads();
            if (t==0){
                Wcum[k+1] = Wtot;
                __hip_atomic_store(flag, k+1, __ATOMIC_RELEASE, __HIP_MEMORY_SCOPE_AGENT);
            }
        }
        if (t==0){
            mist[0] = Wtot;
            #pragma unroll
            for (int c=0;c<C;c++) anf[c] = an[c];
        }
    } else {
        // ---------------- corrector (bx in 1..CWG): ROWS rows per target block ----------------
        const int R0base = (bx-1)*ROWS;
        // prologue: S_final(block 0) = S0 (no wrongs yet)
        if (t < ROWS*C){
            int r = t / C, c = t % C;
            Sfin[(size_t)(R0base + r)*C + c] = S0[(size_t)(R0base + r)*C + c];
        }
        __syncthreads();
        if (t==0) __hip_atomic_store(&slots[bx*32], 0, __ATOMIC_RELEASE,
                                     __HIP_MEMORY_SCOPE_AGENT);

        for (int k=0; k<NB-1; ++k){
            const int R0 = (k+1)*B + R0base;       // rows of block k+1
            float pp[ROWS][C];
            #pragma unroll
            for (int r=0;r<ROWS;r++)
                #pragma unroll
                for (int c=0;c<C;c++) pp[r][c]=0.f;

            int W0 = Wcum[k];                      // wrongs through block k-1 (visible)
            // ---- phase A (overlaps seq(k)): corrections from old wrongs ----
            for (int w=0; w<W0; ++w){
                int pk = wrongList[w];
                int gw = pk & 4095, pcl=(pk>>12)&15, lcl=(pk>>16)&15;
                const float4* xw = X4 + (size_t)gw*D4;
                float gg[ROWS];
                #pragma unroll
                for (int r=0;r<ROWS;r++) gg[r]=0.f;
                for (int d=t; d<D4; d+=256){
                    float4 v = xw[d];
                    #pragma unroll
                    for (int r=0;r<ROWS;r++){
                        float4 a = X4[(size_t)(R0+r)*D4 + d];
                        gg[r] += a.x*v.x + a.y*v.y + a.z*v.z + a.w*v.w;
                    }
                }
                #pragma unroll
                for (int c=0;c<C;c++){
                    float sg = ((c==lcl)?1.f:0.f) - ((c==pcl)?1.f:0.f);
                    #pragma unroll
                    for (int r=0;r<ROWS;r++) pp[r][c] += sg*gg[r];
                }
            }
            // ---- wait for seq(k)'s wrongs ----
            if (t==0){
                while (__hip_atomic_load(flag, __ATOMIC_RELAXED,
                                         __HIP_MEMORY_SCOPE_AGENT) < k+1)
                    __builtin_amdgcn_s_sleep(1);
                (void)__hip_atomic_load(flag, __ATOMIC_ACQUIRE, __HIP_MEMORY_SCOPE_AGENT);
            }
            __syncthreads();
            int W1 = Wcum[k+1];
            // ---- phase B: tail corrections from block k's fresh wrongs ----
            for (int w=W0; w<W1; ++w){
                int pk = wrongList[w];
                int gw = pk & 4095, pcl=(pk>>12)&15, lcl=(pk>>16)&15;
                const float4* xw = X4 + (size_t)gw*D4;
                float gg[ROWS];
                #pragma unroll
                for (int r=0;r<ROWS;r++) gg[r]=0.f;
                for (int d=t; d<D4; d+=256){
                    float4 v = xw[d];
                    #pragma unroll
                    for (int r=0;r<ROWS;r++){
                        float4 a = X4[(size_t)(R0+r)*D4 + d];
                        gg[r] += a.x*v.x + a.y*v.y + a.z*v.z + a.w*v.w;
                    }
                }
                #pragma unroll
                for (int c=0;c<C;c++){
                    float sg = ((c==lcl)?1.f:0.f) - ((c==pcl)?1.f:0.f);
                    #pragma unroll
                    for (int r=0;r<ROWS;r++) pp[r][c] += sg*gg[r];
                }
            }
            // ---- reduce + write S_final(k+1) ----
            if (W1 == 0){
                if (t < ROWS*C){
                    int r = t / C, c = t % C;
                    Sfin[(size_t)(R0 + r)*C + c] = S0[(size_t)(R0 + r)*C + c];
                }
            } else {
                __shared__ float red[ROWS][C][4];
                int wid=t>>6, lane=t&63;
                #pragma unroll
                for (int r=0;r<ROWS;r++)
                    #pragma unroll
                    for (int c=0;c<C;c++){
                        float x = pp[r][c];
                        #pragma unroll
                        for (int off=32; off>=1; off>>=1) x += __shfl_down(x, off);
                        if (lane==0) red[r][c][wid] = x;
                    }
                __syncthreads();
                if (t < ROWS*C){
                    int r = t / C, c = t % C;
                    float v = red[r][c][0]+red[r][c][1]+red[r][c][2]+red[r][c][3];
                    Sfin[(size_t)(R0 + r)*C + c] = S0[(size_t)(R0 + r)*C + c] + v;
                }
            }
            __syncthreads();
            if (t==0) __hip_atomic_store(&slots[bx*32], k+1, __ATOMIC_RELEASE,
                                         __HIP_MEMORY_SCOPE_AGENT);
        }
    }
}

// ---------------- apply ALL wrongs to am0 once (exclusive float4 columns) ----------------
__global__ __launch_bounds__(256) void apply_final_kernel(float* __restrict__ am,
        const float* __restrict__ X, const int* __restrict__ wrongList,
        const int* __restrict__ Wcum){
    int d4 = blockIdx.x*256 + threadIdx.x;
    if (d4 >= D4) return;
    int W = Wcum[NB];
    const float4* X4 = (const float4*)X;
    float4 acc[C];
    #pragma unroll
    for (int c=0;c<C;c++) acc[c] = make_float4(0.f,0.f,0.f,0.f);
    int touched = 0;
    for (int w=0; w<W; ++w){
        int pk = wrongList[w];
        int gw = pk & 4095, pcl=(pk>>12)&15, lcl=(pk>>16)&15;
        touched |= (1<<pcl) | (1<<lcl);
        float4 x = X4[(size_t)gw*D4 + d4];
        #pragma unroll
        for (int c=0;c<C;c++){
            float coef = ((c==lcl)?1.f:0.f) - ((c==pcl)?1.f:0.f);
            acc[c].x += coef*x.x; acc[c].y += coef*x.y;
            acc[c].z += coef*x.z; acc[c].w += coef*x.w;
        }
    }
    float4* am4 = (float4*)am;
    #pragma unroll
    for (int c=0;c<C;c++){
        if (touched & (1<<c)){
            float4 v = am4[(size_t)c*D4 + d4];
            v.x += acc[c].x; v.y += acc[c].y; v.z += acc[c].z; v.w += acc[c].w;
            am4[(size_t)c*D4 + d4] = v;
        }
    }
}

// ---------------- final predict: 4 rows/WG, float4, am reuse in registers ----------------
__global__ __launch_bounds__(256) void predict_kernel(const float* __restrict__ am,
        const float* __restrict__ X, const float* __restrict__ anf, float* __restrict__ outPred){
    int i0 = blockIdx.x*4, t = threadIdx.x;
    const float4* a4 = (const float4*)am;
    const float4* X4 = (const float4*)X;
    float p[4][C];
    #pragma unroll
    for (int r=0;r<4;r++)
        #pragma unroll
        for (int c=0;c<C;c++) p[r][c]=0.f;
    for (int d=t; d<D4; d+=256){
        float4 x0 = X4[(size_t)(i0+0)*D4 + d];
        float4 x1 = X4[(size_t)(i0+1)*D4 + d];
        float4 x2 = X4[(size_t)(i0+2)*D4 + d];
        float4 x3 = X4[(size_t)(i0+3)*D4 + d];
        #pragma unroll
        for (int c=0;c<C;c++){
            float4 a = a4[(size_t)c*D4 + d];
            p[0][c] += x0.x*a.x + x0.y*a.y + x0.z*a.z + x0.w*a.w;
            p[1][c] += x1.x*a.x + x1.y*a.y + x1.z*a.z + x1.w*a.w;
            p[2][c] += x2.x*a.x + x2.y*a.y + x2.z*a.z + x2.w*a.w;
            p[3][c] += x3.x*a.x + x3.y*a.y + x3.z*a.z + x3.w*a.w;
        }
    }
    __shared__ float red[4][C][4];
    int wid=t>>6, lane=t&63;
    #pragma unroll
    for (int r=0;r<4;r++)
        #pragma unroll
        for (int c=0;c<C;c++){
            float x = p[r][c];
            #pragma unroll
            for (int off=32; off>=1; off>>=1) x += __shfl_down(x, off);
            if (lane==0) red[r][c][wid] = x;
        }
    __syncthreads();
    if (t < 4){
        float best = -3.4e38f; int bi = 0;
        #pragma unroll
        for (int c=0;c<C;c++){
            float dot = red[t][c][0]+red[t][c][1]+red[t][c][2]+red[t][c][3];
            float v = dot * rsqrtf(anf[c]);
            if (v > best){ best = v; bi = c; }
        }
        outPred[i0 + t] = (float)bi;
    }
}

// ---------------- am copy + mistakes scalar ----------------
__global__ __launch_bounds__(256) void finalize_kernel(const float* __restrict__ am,
        const int* __restrict__ mistakes, float* __restrict__ out){
    int i = blockIdx.x*256 + threadIdx.x;
    if (i < C*D) out[i] = am[i];
    if (i == 0) out[C*D + N] = (float)(*mistakes);
}

extern "C" void kernel_launch(void* const* d_in, const int* in_sizes, int n_in,
                              void* d_out, int out_size, void* d_ws, size_t ws_size,
                              hipStream_t stream){
    const float* X      = (const float*)d_in[0];
    const int*   labels = (const int*)d_in[1];
    float* ws   = (float*)d_ws;
    float* am   = ws + AM_OFF;
    float* Gloc = ws + GLOC_OFF;
    float* S0   = ws + S0_OFF;
    float* Sfin = ws + SFIN_OFF;
    float* hv2  = ws + HV2_OFF;
    float* an   = ws + AN_OFF;
    float* anf  = ws + ANF_OFF;
    int*   wlist = (int*)(ws + WLIST_OFF);
    int*   wcum  = (int*)(ws + WCUM_OFF);
    int*   slots = (int*)(ws + SLOTS_OFF);
    int*   flag  = (int*)(ws + FLAG_OFF);
    int*   mist  = (int*)(ws + MIST_OFF);
    float* out = (float*)d_out;

    hipMemsetAsync(am,    0,    (size_t)C*D*sizeof(float), stream);
    hipMemsetAsync(Gloc,  0,    (size_t)NB*B*B*sizeof(float), stream);
    hipMemsetAsync(wcum,  0,    32*sizeof(int), stream);
    hipMemsetAsync(slots, 0xFF, (RWG*32 + 8)*sizeof(int), stream);  // slots + flag = -1

    build_am_kernel<<<dim3(10,16), 256, 0, stream>>>(am, X, labels);
    rownorm2_kernel<<<C, 256, 0, stream>>>(am, an);
    gram_kernel<<<dim3(80,NB), 256, 0, stream>>>(X, Gloc);
    s0_kernel<<<N/4, 256, 0, stream>>>(am, X, S0, hv2);

    retrain_kernel<<<RWG, 256, 0, stream>>>(X, labels, Gloc, S0, Sfin, hv2,
                                            an, anf, wlist, wcum, slots, flag, mist);

    apply_final_kernel<<<10, 256, 0, stream>>>(am, X, wlist, wcum);
    predict_kernel<<<N/4, 256, 0, stream>>>(am, X, anf, out + (size_t)C*D);
    finalize_kernel<<<(C*D + 255)/256 + 1, 256, 0, stream>>>(am, mist, out);
}

// Round 8
// 828.059 us; speedup vs baseline: 3.0485x; 1.8031x over previous
//
#include <hip/hip_runtime.h>

#define N 4096
#define D 10000
#define D4 2500          // D/4
#define C 10
#define NB 16            // number of 256-step blocks
#define B 256            // steps per block
#define CWG 32           // corrector WGs
#define ROWS 8           // rows per corrector WG
#define RWG (CWG + 1)    // retrain grid size

// ---- workspace layout (float offsets) ----
#define AM_OFF    0                            // [C*D] = 100000 (pad 100096)
#define GLOC_OFF  100096                       // [16][256][256]
#define S0_OFF    (GLOC_OFF + NB*B*B)          // [N*C] initial scores
#define SFIN_OFF  (S0_OFF + N*C)               // [N*C] corrected scores
#define HV2_OFF   (SFIN_OFF + N*C)             // [N]
#define AN_OFF    (HV2_OFF + N)                // [16] initial ||am_c||^2
#define ANF_OFF   (AN_OFF + 16)                // [16] final   ||am_c||^2
#define WLIST_OFF (ANF_OFF + 16)               // [N] packed gidx|pred<<12|lab<<16
#define WCUM_OFF  (WLIST_OFF + N)              // [32] ints, Wcum[k]=wrongs before block k
#define SLOTS_OFF (WCUM_OFF + 32)              // [RWG*32] ints, stride-32 arrival slots
#define FLAG_OFF  (SLOTS_OFF + RWG*32)         // [1] int
#define MIST_OFF  (FLAG_OFF + 8)               // [1] int

// ---------------- build_am: segment-sum, float4, register accumulate + atomics ------------
__global__ __launch_bounds__(256) void build_am_kernel(float* __restrict__ am,
        const float* __restrict__ X, const int* __restrict__ labels){
    int d4 = blockIdx.x*256 + threadIdx.x;
    if (d4 >= D4) return;
    int i0 = blockIdx.y * (N/16);
    const float4* X4 = (const float4*)X;
    float4 acc[C];
    #pragma unroll
    for (int c=0;c<C;c++) acc[c] = make_float4(0.f,0.f,0.f,0.f);
    for (int i=i0; i<i0+(N/16); ++i){
        int lab = labels[i];
        float4 x = X4[(size_t)i*D4 + d4];
        #pragma unroll
        for (int c=0;c<C;c++){
            float m = (lab==c) ? 1.f : 0.f;
            acc[c].x += m*x.x; acc[c].y += m*x.y; acc[c].z += m*x.z; acc[c].w += m*x.w;
        }
    }
    #pragma unroll
    for (int c=0;c<C;c++){
        float* p = &am[(size_t)c*D + d4*4];
        atomicAdd(p+0, acc[c].x); atomicAdd(p+1, acc[c].y);
        atomicAdd(p+2, acc[c].z); atomicAdd(p+3, acc[c].w);
    }
}

// ---------------- row sum-of-squares of am -> out[c] ----------------
__global__ __launch_bounds__(256) void rownorm2_kernel(const float* __restrict__ am,
        float* __restrict__ out){
    int c = blockIdx.x, t = threadIdx.x;
    const float4* a4 = (const float4*)(am + (size_t)c*D);
    float p = 0.f;
    for (int d=t; d<D4; d+=256){ float4 v = a4[d]; p += v.x*v.x+v.y*v.y+v.z*v.z+v.w*v.w; }
    #pragma unroll
    for (int off=32; off>=1; off>>=1) p += __shfl_down(p, off);
    __shared__ float wsum[4];
    int wid = t>>6, lane = t&63;
    if (lane==0) wsum[wid]=p;
    __syncthreads();
    if (t==0) out[c] = wsum[0]+wsum[1]+wsum[2]+wsum[3];
}

// ---------------- block-diagonal Gram tiles (fp32, LDS XOR-swizzled, K-split) --------------
__global__ __launch_bounds__(256) void gram_kernel(const float* __restrict__ X,
        float* __restrict__ Gloc){
    __shared__ float Asm[32][68];
    __shared__ float Bsm[32][68];
    int bx = blockIdx.x;
    int k  = blockIdx.y;
    int p  = bx % 10;
    int z  = bx / 10;
    int ti = (p<4)?0:(p<7)?1:(p<9)?2:3;
    int st = (ti==0)?0:(ti==1)?4:(ti==2)?7:9;
    int tj = ti + (p - st);
    int rowA = k*B + ti*64;
    int rowB = k*B + tj*64;
    int t = threadIdx.x;
    int tx = t & 15, ty = t >> 4;
    float acc[4][4];
    #pragma unroll
    for (int i=0;i<4;i++)
        #pragma unroll
        for (int j=0;j<4;j++) acc[i][j]=0.f;

    for (int ch = z; ch*32 < D; ch += 8){
        int dbase = ch*32;
        int valid = D - dbase; if (valid > 32) valid = 32;
        #pragma unroll
        for (int f0 = 0; f0 < 512; f0 += 256){
            int f = f0 + t;
            int row = f >> 3, q = f & 7;
            float4 a = make_float4(0,0,0,0), b = make_float4(0,0,0,0);
            if (q*4 < valid){
                a = *(const float4*)&X[(size_t)(rowA + row)*D + dbase + q*4];
                b = *(const float4*)&X[(size_t)(rowB + row)*D + dbase + q*4];
            }
            int pr = row ^ (q<<3);
            Asm[q*4+0][pr]=a.x; Asm[q*4+1][pr]=a.y; Asm[q*4+2][pr]=a.z; Asm[q*4+3][pr]=a.w;
            Bsm[q*4+0][pr]=b.x; Bsm[q*4+1][pr]=b.y; Bsm[q*4+2][pr]=b.z; Bsm[q*4+3][pr]=b.w;
        }
        __syncthreads();
        #pragma unroll 4
        for (int dd=0; dd<32; ++dd){
            int sw = ((dd>>2)&7)<<3;
            const float4 av = *(const float4*)&Asm[dd][(ty*4) ^ sw];
            const float4 bv = *(const float4*)&Bsm[dd][(tx*4) ^ sw];
            float a4[4] = {av.x, av.y, av.z, av.w};
            float b4[4] = {bv.x, bv.y, bv.z, bv.w};
            #pragma unroll
            for (int i=0;i<4;i++)
                #pragma unroll
                for (int j=0;j<4;j++) acc[i][j] += a4[i]*b4[j];
        }
        __syncthreads();
    }
    float* G = Gloc + (size_t)k*B*B;
    int abase = ti*64 + ty*4;
    int bbase = tj*64 + tx*4;
    #pragma unroll
    for (int i=0;i<4;i++)
        #pragma unroll
        for (int j=0;j<4;j++)
            atomicAdd(&G[(abase+i)*B + (bbase+j)], acc[i][j]);
}

// ---------------- S0[j][c] = am0_c . hv_j for ALL samples (+ hv2), 4 rows/WG ----------------
__global__ __launch_bounds__(256) void s0_kernel(const float* __restrict__ am,
        const float* __restrict__ X, float* __restrict__ S0, float* __restrict__ hv2){
    int gj0 = blockIdx.x*4;
    int t = threadIdx.x;
    const float4* X4 = (const float4*)X;
    const float4* a4 = (const float4*)am;
    float p[4][C]; float px[4];
    #pragma unroll
    for (int r=0;r<4;r++){ px[r]=0.f;
        #pragma unroll
        for (int c=0;c<C;c++) p[r][c]=0.f; }
    for (int d=t; d<D4; d+=256){
        float4 x0 = X4[(size_t)(gj0+0)*D4 + d];
        float4 x1 = X4[(size_t)(gj0+1)*D4 + d];
        float4 x2 = X4[(size_t)(gj0+2)*D4 + d];
        float4 x3 = X4[(size_t)(gj0+3)*D4 + d];
        px[0] += x0.x*x0.x + x0.y*x0.y + x0.z*x0.z + x0.w*x0.w;
        px[1] += x1.x*x1.x + x1.y*x1.y + x1.z*x1.z + x1.w*x1.w;
        px[2] += x2.x*x2.x + x2.y*x2.y + x2.z*x2.z + x2.w*x2.w;
        px[3] += x3.x*x3.x + x3.y*x3.y + x3.z*x3.z + x3.w*x3.w;
        #pragma unroll
        for (int c=0;c<C;c++){
            float4 a = a4[(size_t)c*D4 + d];
            p[0][c] += x0.x*a.x + x0.y*a.y + x0.z*a.z + x0.w*a.w;
            p[1][c] += x1.x*a.x + x1.y*a.y + x1.z*a.z + x1.w*a.w;
            p[2][c] += x2.x*a.x + x2.y*a.y + x2.z*a.z + x2.w*a.w;
            p[3][c] += x3.x*a.x + x3.y*a.y + x3.z*a.z + x3.w*a.w;
        }
    }
    __shared__ float red[4][C+1][4];
    int wid=t>>6, lane=t&63;
    #pragma unroll
    for (int r=0;r<4;r++){
        #pragma unroll
        for (int v=0; v<C+1; ++v){
            float x = (v<C)? p[r][v] : px[r];
            #pragma unroll
            for (int off=32; off>=1; off>>=1) x += __shfl_down(x, off);
            if (lane==0) red[r][v][wid] = x;
        }
    }
    __syncthreads();
    if (t < 4*(C+1)){
        int r = t/(C+1), v = t%(C+1);
        float s = red[r][v][0]+red[r][v][1]+red[r][v][2]+red[r][v][3];
        if (v < C) S0[(size_t)(gj0+r)*C + v] = s;
        else hv2[gj0 + r] = s;
    }
}

// ================= retrain: WG0 = sequencer (speculative scan), WGs 1..32 = correctors =====
__global__ __launch_bounds__(256) void retrain_kernel(
        const float* __restrict__ X, const int* __restrict__ labels,
        const float* __restrict__ Gloc, const float* __restrict__ S0,
        float* __restrict__ Sfin, const float* __restrict__ hv2g,
        const float* __restrict__ an0, float* __restrict__ anf,
        int* __restrict__ wrongList, int* __restrict__ Wcum,
        int* slots, int* flag, int* __restrict__ mist){
    const int bx = blockIdx.x, t = threadIdx.x;
    const float4* X4 = (const float4*)X;

    if (bx == 0){
        // ---------------- sequencer ----------------
        float an[C], rstd[C];
        #pragma unroll
        for (int c=0;c<C;c++){ an[c]=an0[c]; rstd[c]=rsqrtf(an[c]); }
        int Wtot = 0;
        for (int k=0; k<NB; ++k){
            // wait: S_final(k) complete (correctors' slot >= k)
            if (t < CWG){
                while (__hip_atomic_load(&slots[(1+t)*32], __ATOMIC_RELAXED,
                                         __HIP_MEMORY_SCOPE_AGENT) < k)
                    __builtin_amdgcn_s_sleep(1);
            }
            __syncthreads();
            if (t==0) (void)__hip_atomic_load(&slots[32], __ATOMIC_ACQUIRE,
                                              __HIP_MEMORY_SCOPE_AGENT);
            __syncthreads();

            if (t < 64){
                const int lane = t;
                const int base = k*B;
                const float* G = Gloc + (size_t)k*B*B;
                float s[4][C];
                float h2o[4]; int labo[4];
                #pragma unroll
                for (int q=0;q<4;q++){
                    int j = q*64 + lane;
                    #pragma unroll
                    for (int c=0;c<C;c++) s[q][c] = Sfin[(size_t)(base+j)*C + c];
                    h2o[q] = hv2g[base + j];
                    labo[q] = labels[base + j];
                }
                int myPred[4], myWrong[4];
                #pragma unroll
                for (int q=0;q<4;q++){ myPred[q]=0; myWrong[q]=0; }

                // ---- speculative scan: parallel decisions, process wrongs as events ----
                int pos = -1;
                while (true){
                    // 1. all lanes decide their own samples (no cross-lane deps)
                    int pred[4];
                    #pragma unroll
                    for (int q=0;q<4;q++){
                        float best = s[q][0]*rstd[0]; int bi=0;
                        #pragma unroll
                        for (int c=1;c<C;c++){
                            float v = s[q][c]*rstd[c];
                            if (v>best){best=v;bi=c;}
                        }
                        pred[q]=bi;
                    }
                    // 2. first wrong with j > pos (q ascending gives global min)
                    int jstar = 256;
                    #pragma unroll
                    for (int q=0;q<4;q++){
                        unsigned long long m =
                            __ballot((pred[q]!=labo[q]) && (q*64+lane > pos));
                        if (jstar==256 && m!=0ull)
                            jstar = q*64 + (__ffsll((unsigned long long)m)-1);
                    }
                    // 3. record decisions for pos < j <= jstar (or all if none wrong)
                    #pragma unroll
                    for (int q=0;q<4;q++){
                        int j = q*64+lane;
                        if (j>pos && j<=jstar){
                            myPred[q]=pred[q];
                            myWrong[q]=(j==jstar)?1:0;
                        }
                    }
                    if (jstar >= 256) break;
                    // 4. process the wrong at jstar (uniform)
                    int qs = jstar>>6, ls = jstar&63;
                    float sqs[C];
                    #pragma unroll
                    for (int c=0;c<C;c++)
                        sqs[c] = (qs==0)? s[0][c] : (qs==1)? s[1][c]
                               : (qs==2)? s[2][c] : s[3][c];
                    int predqs = (qs==0)? pred[0] : (qs==1)? pred[1]
                               : (qs==2)? pred[2] : pred[3];
                    int labqs  = (qs==0)? labo[0] : (qs==1)? labo[1]
                               : (qs==2)? labo[2] : labo[3];
                    float h2qs = (qs==0)? h2o[0] : (qs==1)? h2o[1]
                               : (qs==2)? h2o[2] : h2o[3];
                    float brawme = sqs[0], slvme = sqs[0];
                    #pragma unroll
                    for (int c=1;c<C;c++){
                        brawme = (c==predqs)? sqs[c] : brawme;
                        slvme  = (c==labqs)?  sqs[c] : slvme;
                    }
                    float brawB = __shfl(brawme, ls);
                    float slvB  = __shfl(slvme,  ls);
                    float h2b   = __shfl(h2qs,   ls);
                    int   pkB   = __shfl(predqs | (labqs<<8), ls);
                    int biB = pkB & 255, labB = (pkB>>8) & 255;
                    if (lane==0)
                        wrongList[Wtot] = (base + jstar) | (biB<<12) | (labB<<16);
                    Wtot++;
                    // norm updates
                    float anp = an[0], anl = an[0];
                    #pragma unroll
                    for (int c=1;c<C;c++){ anp=(c==biB)?an[c]:anp; anl=(c==labB)?an[c]:anl; }
                    float anp_new = anp - 2.f*brawB + h2b;
                    float anl_new = anl + 2.f*slvB  + h2b;
                    float rp = rsqrtf(anp_new), rl = rsqrtf(anl_new);
                    #pragma unroll
                    for (int c=0;c<C;c++){
                        an[c]   = (c==biB)? anp_new : (c==labB)? anl_new : an[c];
                        rstd[c] = (c==biB)? rp      : (c==labB)? rl      : rstd[c];
                    }
                    // 5. propagate G row jstar into all lanes' future samples
                    //    (zero lower-triangle blocks make past-sample updates no-ops)
                    float grow[4];
                    #pragma unroll
                    for (int sl=0;sl<4;sl++)
                        grow[sl] = G[(size_t)jstar*B + sl*64 + lane];
                    #pragma unroll
                    for (int c=0;c<C;c++){
                        float sg = (c==biB)? -1.f : (c==labB)? 1.f : 0.f;
                        #pragma unroll
                        for (int sl=0;sl<4;sl++) s[sl][c] += sg * grow[sl];
                    }
                    pos = jstar;
                }
            }
            __syncthreads();
            // Wtot lives uniformly in wave-0 lanes; publish from t==0
            if (t==0){
                Wcum[k+1] = Wtot;
                __hip_atomic_store(flag, k+1, __ATOMIC_RELEASE, __HIP_MEMORY_SCOPE_AGENT);
            }
        }
        if (t==0){
            mist[0] = Wtot;
            #pragma unroll
            for (int c=0;c<C;c++) anf[c] = an[c];
        }
    } else {
        // ---------------- corrector (bx in 1..CWG): ROWS rows per target block ----------------
        const int R0base = (bx-1)*ROWS;
        if (t < ROWS*C){
            int r = t / C, c = t % C;
            Sfin[(size_t)(R0base + r)*C + c] = S0[(size_t)(R0base + r)*C + c];
        }
        __syncthreads();
        if (t==0) __hip_atomic_store(&slots[bx*32], 0, __ATOMIC_RELEASE,
                                     __HIP_MEMORY_SCOPE_AGENT);

        for (int k=0; k<NB-1; ++k){
            const int R0 = (k+1)*B + R0base;       // rows of block k+1
            float pp[ROWS][C];
            #pragma unroll
            for (int r=0;r<ROWS;r++)
                #pragma unroll
                for (int c=0;c<C;c++) pp[r][c]=0.f;

            int W0 = Wcum[k];                      // wrongs through block k-1 (visible)
            // ---- phase A (overlaps seq(k)): corrections from old wrongs ----
            for (int w=0; w<W0; ++w){
                int pk = wrongList[w];
                int gw = pk & 4095, pcl=(pk>>12)&15, lcl=(pk>>16)&15;
                const float4* xw = X4 + (size_t)gw*D4;
                float gg[ROWS];
                #pragma unroll
                for (int r=0;r<ROWS;r++) gg[r]=0.f;
                for (int d=t; d<D4; d+=256){
                    float4 v = xw[d];
                    #pragma unroll
                    for (int r=0;r<ROWS;r++){
                        float4 a = X4[(size_t)(R0+r)*D4 + d];
                        gg[r] += a.x*v.x + a.y*v.y + a.z*v.z + a.w*v.w;
                    }
                }
                #pragma unroll
                for (int c=0;c<C;c++){
                    float sg = ((c==lcl)?1.f:0.f) - ((c==pcl)?1.f:0.f);
                    #pragma unroll
                    for (int r=0;r<ROWS;r++) pp[r][c] += sg*gg[r];
                }
            }
            // ---- wait for seq(k)'s wrongs ----
            if (t==0){
                while (__hip_atomic_load(flag, __ATOMIC_RELAXED,
                                         __HIP_MEMORY_SCOPE_AGENT) < k+1)
                    __builtin_amdgcn_s_sleep(1);
                (void)__hip_atomic_load(flag, __ATOMIC_ACQUIRE, __HIP_MEMORY_SCOPE_AGENT);
            }
            __syncthreads();
            int W1 = Wcum[k+1];
            // ---- phase B: tail corrections from block k's fresh wrongs ----
            for (int w=W0; w<W1; ++w){
                int pk = wrongList[w];
                int gw = pk & 4095, pcl=(pk>>12)&15, lcl=(pk>>16)&15;
                const float4* xw = X4 + (size_t)gw*D4;
                float gg[ROWS];
                #pragma unroll
                for (int r=0;r<ROWS;r++) gg[r]=0.f;
                for (int d=t; d<D4; d+=256){
                    float4 v = xw[d];
                    #pragma unroll
                    for (int r=0;r<ROWS;r++){
                        float4 a = X4[(size_t)(R0+r)*D4 + d];
                        gg[r] += a.x*v.x + a.y*v.y + a.z*v.z + a.w*v.w;
                    }
                }
                #pragma unroll
                for (int c=0;c<C;c++){
                    float sg = ((c==lcl)?1.f:0.f) - ((c==pcl)?1.f:0.f);
                    #pragma unroll
                    for (int r=0;r<ROWS;r++) pp[r][c] += sg*gg[r];
                }
            }
            // ---- reduce + write S_final(k+1) ----
            if (W1 == 0){
                if (t < ROWS*C){
                    int r = t / C, c = t % C;
                    Sfin[(size_t)(R0 + r)*C + c] = S0[(size_t)(R0 + r)*C + c];
                }
            } else {
                __shared__ float red[ROWS][C][4];
                int wid=t>>6, lane=t&63;
                #pragma unroll
                for (int r=0;r<ROWS;r++)
                    #pragma unroll
                    for (int c=0;c<C;c++){
                        float x = pp[r][c];
                        #pragma unroll
                        for (int off=32; off>=1; off>>=1) x += __shfl_down(x, off);
                        if (lane==0) red[r][c][wid] = x;
                    }
                __syncthreads();
                if (t < ROWS*C){
                    int r = t / C, c = t % C;
                    float v = red[r][c][0]+red[r][c][1]+red[r][c][2]+red[r][c][3];
                    Sfin[(size_t)(R0 + r)*C + c] = S0[(size_t)(R0 + r)*C + c] + v;
                }
            }
            __syncthreads();
            if (t==0) __hip_atomic_store(&slots[bx*32], k+1, __ATOMIC_RELEASE,
                                         __HIP_MEMORY_SCOPE_AGENT);
        }
    }
}

// ---------------- apply ALL wrongs to am0 once (exclusive float4 columns) ----------------
__global__ __launch_bounds__(256) void apply_final_kernel(float* __restrict__ am,
        const float* __restrict__ X, const int* __restrict__ wrongList,
        const int* __restrict__ Wcum){
    int d4 = blockIdx.x*256 + threadIdx.x;
    if (d4 >= D4) return;
    int W = Wcum[NB];
    const float4* X4 = (const float4*)X;
    float4 acc[C];
    #pragma unroll
    for (int c=0;c<C;c++) acc[c] = make_float4(0.f,0.f,0.f,0.f);
    int touched = 0;
    for (int w=0; w<W; ++w){
        int pk = wrongList[w];
        int gw = pk & 4095, pcl=(pk>>12)&15, lcl=(pk>>16)&15;
        touched |= (1<<pcl) | (1<<lcl);
        float4 x = X4[(size_t)gw*D4 + d4];
        #pragma unroll
        for (int c=0;c<C;c++){
            float coef = ((c==lcl)?1.f:0.f) - ((c==pcl)?1.f:0.f);
            acc[c].x += coef*x.x; acc[c].y += coef*x.y;
            acc[c].z += coef*x.z; acc[c].w += coef*x.w;
        }
    }
    float4* am4 = (float4*)am;
    #pragma unroll
    for (int c=0;c<C;c++){
        if (touched & (1<<c)){
            float4 v = am4[(size_t)c*D4 + d4];
            v.x += acc[c].x; v.y += acc[c].y; v.z += acc[c].z; v.w += acc[c].w;
            am4[(size_t)c*D4 + d4] = v;
        }
    }
}

// ---------------- final predict: 4 rows/WG, float4, am reuse in registers ----------------
__global__ __launch_bounds__(256) void predict_kernel(const float* __restrict__ am,
        const float* __restrict__ X, const float* __restrict__ anf, float* __restrict__ outPred){
    int i0 = blockIdx.x*4, t = threadIdx.x;
    const float4* a4 = (const float4*)am;
    const float4* X4 = (const float4*)X;
    float p[4][C];
    #pragma unroll
    for (int r=0;r<4;r++)
        #pragma unroll
        for (int c=0;c<C;c++) p[r][c]=0.f;
    for (int d=t; d<D4; d+=256){
        float4 x0 = X4[(size_t)(i0+0)*D4 + d];
        float4 x1 = X4[(size_t)(i0+1)*D4 + d];
        float4 x2 = X4[(size_t)(i0+2)*D4 + d];
        float4 x3 = X4[(size_t)(i0+3)*D4 + d];
        #pragma unroll
        for (int c=0;c<C;c++){
            float4 a = a4[(size_t)c*D4 + d];
            p[0][c] += x0.x*a.x + x0.y*a.y + x0.z*a.z + x0.w*a.w;
            p[1][c] += x1.x*a.x + x1.y*a.y + x1.z*a.z + x1.w*a.w;
            p[2][c] += x2.x*a.x + x2.y*a.y + x2.z*a.z + x2.w*a.w;
            p[3][c] += x3.x*a.x + x3.y*a.y + x3.z*a.z + x3.w*a.w;
        }
    }
    __shared__ float red[4][C][4];
    int wid=t>>6, lane=t&63;
    #pragma unroll
    for (int r=0;r<4;r++)
        #pragma unroll
        for (int c=0;c<C;c++){
            float x = p[r][c];
            #pragma unroll
            for (int off=32; off>=1; off>>=1) x += __shfl_down(x, off);
            if (lane==0) red[r][c][wid] = x;
        }
    __syncthreads();
    if (t < 4){
        float best = -3.4e38f; int bi = 0;
        #pragma unroll
        for (int c=0;c<C;c++){
            float dot = red[t][c][0]+red[t][c][1]+red[t][c][2]+red[t][c][3];
            float v = dot * rsqrtf(anf[c]);
            if (v > best){ best = v; bi = c; }
        }
        outPred[i0 + t] = (float)bi;
    }
}

// ---------------- am copy + mistakes scalar ----------------
__global__ __launch_bounds__(256) void finalize_kernel(const float* __restrict__ am,
        const int* __restrict__ mistakes, float* __restrict__ out){
    int i = blockIdx.x*256 + threadIdx.x;
    if (i < C*D) out[i] = am[i];
    if (i == 0) out[C*D + N] = (float)(*mistakes);
}

extern "C" void kernel_launch(void* const* d_in, const int* in_sizes, int n_in,
                              void* d_out, int out_size, void* d_ws, size_t ws_size,
                              hipStream_t stream){
    const float* X      = (const float*)d_in[0];
    const int*   labels = (const int*)d_in[1];
    float* ws   = (float*)d_ws;
    float* am   = ws + AM_OFF;
    float* Gloc = ws + GLOC_OFF;
    float* S0   = ws + S0_OFF;
    float* Sfin = ws + SFIN_OFF;
    float* hv2  = ws + HV2_OFF;
    float* an   = ws + AN_OFF;
    float* anf  = ws + ANF_OFF;
    int*   wlist = (int*)(ws + WLIST_OFF);
    int*   wcum  = (int*)(ws + WCUM_OFF);
    int*   slots = (int*)(ws + SLOTS_OFF);
    int*   flag  = (int*)(ws + FLAG_OFF);
    int*   mist  = (int*)(ws + MIST_OFF);
    float* out = (float*)d_out;

    hipMemsetAsync(am,    0,    (size_t)C*D*sizeof(float), stream);
    hipMemsetAsync(Gloc,  0,    (size_t)NB*B*B*sizeof(float), stream);
    hipMemsetAsync(wcum,  0,    32*sizeof(int), stream);
    hipMemsetAsync(slots, 0xFF, (RWG*32 + 8)*sizeof(int), stream);  // slots + flag = -1

    build_am_kernel<<<dim3(10,16), 256, 0, stream>>>(am, X, labels);
    rownorm2_kernel<<<C, 256, 0, stream>>>(am, an);
    gram_kernel<<<dim3(80,NB), 256, 0, stream>>>(X, Gloc);
    s0_kernel<<<N/4, 256, 0, stream>>>(am, X, S0, hv2);

    retrain_kernel<<<RWG, 256, 0, stream>>>(X, labels, Gloc, S0, Sfin, hv2,
                                            an, anf, wlist, wcum, slots, flag, mist);

    apply_final_kernel<<<10, 256, 0, stream>>>(am, X, wlist, wcum);
    predict_kernel<<<N/4, 256, 0, stream>>>(am, X, anf, out + (size_t)C*D);
    finalize_kernel<<<(C*D + 255)/256 + 1, 256, 0, stream>>>(am, mist, out);
}